// Round 3
// baseline (113.838 us; speedup 1.0000x reference)
//
#include <hip/hip_runtime.h>

typedef unsigned short u16;
typedef __attribute__((ext_vector_type(8))) __bf16 bf16x8;
typedef __attribute__((ext_vector_type(4))) float f32x4;
typedef __attribute__((ext_vector_type(8))) short short8;
typedef __attribute__((ext_vector_type(4))) u16 us4;

#define T_SEQ 1024
#define PROJW 1280   // P row: Q(512) K(512) QML(128) KML(128); V lives in Vtb

__device__ __forceinline__ u16 f2bf(float f) {
  unsigned u = __float_as_uint(f);
  u += 0x7fff + ((u >> 16) & 1);
  return (u16)(u >> 16);
}

// merged: cvt_x (blocks 0..2047) + prep_w (blocks 2048..)
__global__ void prep_all(const float4* __restrict__ x, u16* __restrict__ xb,
                         const float* __restrict__ Wq, const float* __restrict__ Wk,
                         const float* __restrict__ Wv, const float* __restrict__ Wqml,
                         const float* __restrict__ Wkml, const float* __restrict__ Wp,
                         const float* __restrict__ bq, const float* __restrict__ bk,
                         const float* __restrict__ bv, const float* __restrict__ bqml,
                         const float* __restrict__ bkml,
                         u16* __restrict__ Wcat, u16* __restrict__ Wpx, float* __restrict__ bcat) {
  if (blockIdx.x < 2048) {
    int i = blockIdx.x * 256 + threadIdx.x;
    float4 v = x[i];
    us4 o = { f2bf(v.x), f2bf(v.y), f2bf(v.z), f2bf(v.w) };
    *(us4*)&xb[i * 4] = o;
    return;
  }
  int idx = (blockIdx.x - 2048) * 256 + threadIdx.x;
  const int NW = 1792 * 512;
  if (idx < NW) {
    int row = idx >> 9;
    float v;
    if (row < 512)       v = Wq[idx];
    else if (row < 1024) v = Wk[idx - 512 * 512];
    else if (row < 1536) v = Wv[idx - 1024 * 512];
    else if (row < 1664) v = Wqml[idx - 1536 * 512];
    else                 v = Wkml[idx - 1664 * 512];
    Wcat[idx] = f2bf(v);
    return;
  }
  int i2 = idx - NW;
  if (i2 < 512 * 640) {
    int n = i2 / 640, k2 = i2 - n * 640;
    float v = (k2 < 512) ? Wp[n * 512 + k2] : Wp[n * 512 + k2 - 384];
    Wpx[i2] = f2bf(v);
    return;
  }
  int i3 = i2 - 512 * 640;
  if (i3 < 1792) {
    float v;
    if (i3 < 512)       v = bq[i3];
    else if (i3 < 1024) v = bk[i3 - 512];
    else if (i3 < 1536) v = bv[i3 - 1024];
    else if (i3 < 1664) v = bqml[i3 - 1536];
    else                v = bkml[i3 - 1664];
    bcat[i3] = v;
  }
}

// QKV projection: Q,K,QML,KML -> Pout (row 1280); V -> Vtb transposed [b][512][1024]
__global__ __launch_bounds__(256) void gemm_qkv(
    const u16* __restrict__ A, const u16* __restrict__ Bw,
    const float* __restrict__ bias, u16* __restrict__ Pout, u16* __restrict__ Vtb) {
  __shared__ u16 As[64][40];
  __shared__ u16 Bs[64][40];
  const int tid = threadIdx.x;
  const int lane = tid & 63, w = tid >> 6;
  const int g = lane >> 4, c = lane & 15;
  const int m0 = blockIdx.y * 64, n0 = blockIdx.x * 64;
  const int wr = (w >> 1) * 32, wc = (w & 1) * 32;
  const int arow = tid >> 2, acol = (tid & 3) * 8;

  f32x4 acc[2][2] = {};
  for (int k0 = 0; k0 < 512; k0 += 32) {
    short8 av = *(const short8*)&A[(size_t)(m0 + arow) * 512 + k0 + acol];
    short8 bv = *(const short8*)&Bw[(size_t)(n0 + arow) * 512 + k0 + acol];
    *(short8*)&As[arow][acol] = av;
    *(short8*)&Bs[arow][acol] = bv;
    __syncthreads();
    bf16x8 a0 = *(const bf16x8*)&As[wr + c][g * 8];
    bf16x8 a1 = *(const bf16x8*)&As[wr + 16 + c][g * 8];
    bf16x8 b0 = *(const bf16x8*)&Bs[wc + c][g * 8];
    bf16x8 b1 = *(const bf16x8*)&Bs[wc + 16 + c][g * 8];
    acc[0][0] = __builtin_amdgcn_mfma_f32_16x16x32_bf16(a0, b0, acc[0][0], 0, 0, 0);
    acc[0][1] = __builtin_amdgcn_mfma_f32_16x16x32_bf16(a0, b1, acc[0][1], 0, 0, 0);
    acc[1][0] = __builtin_amdgcn_mfma_f32_16x16x32_bf16(a1, b0, acc[1][0], 0, 0, 0);
    acc[1][1] = __builtin_amdgcn_mfma_f32_16x16x32_bf16(a1, b1, acc[1][1], 0, 0, 0);
    __syncthreads();
  }
  if (n0 >= 1024 && n0 < 1536) {
    for (int fm = 0; fm < 2; ++fm)
      for (int fn = 0; fn < 2; ++fn) {
        int row = m0 + wr + fm * 16 + g * 4;
        int col = n0 + wc + fn * 16 + c;
        float bb = bias[col];
        int d = col - 1024;
        int bidx = row >> 10, t = row & 1023;
        us4 pack = { f2bf(acc[fm][fn][0] + bb), f2bf(acc[fm][fn][1] + bb),
                     f2bf(acc[fm][fn][2] + bb), f2bf(acc[fm][fn][3] + bb) };
        *(us4*)&Vtb[((size_t)bidx * 512 + d) * 1024 + t] = pack;
      }
  } else {
    for (int fm = 0; fm < 2; ++fm)
      for (int fn = 0; fn < 2; ++fn)
        for (int r = 0; r < 4; ++r) {
          int row = m0 + wr + fm * 16 + g * 4 + r;
          int col = n0 + wc + fn * 16 + c;
          int pcol = (col < 1024) ? col : col - 512;
          Pout[(size_t)row * PROJW + pcol] = f2bf(acc[fm][fn][r] + bias[col]);
        }
  }
}

template<bool OUT_BF16>
__global__ __launch_bounds__(256) void gemm_bt(
    const u16* __restrict__ A, int lda,
    const u16* __restrict__ Bw, int ldb,
    const float* __restrict__ bias,
    void* __restrict__ Cout, int ldc, int K) {
  __shared__ u16 As[64][40];
  __shared__ u16 Bs[64][40];
  const int tid = threadIdx.x;
  const int lane = tid & 63, w = tid >> 6;
  const int g = lane >> 4, c = lane & 15;
  const int m0 = blockIdx.y * 64, n0 = blockIdx.x * 64;
  const int wr = (w >> 1) * 32, wc = (w & 1) * 32;
  const int arow = tid >> 2, acol = (tid & 3) * 8;

  f32x4 acc[2][2] = {};
  for (int k0 = 0; k0 < K; k0 += 32) {
    short8 av = *(const short8*)&A[(size_t)(m0 + arow) * lda + k0 + acol];
    short8 bv = *(const short8*)&Bw[(size_t)(n0 + arow) * ldb + k0 + acol];
    *(short8*)&As[arow][acol] = av;
    *(short8*)&Bs[arow][acol] = bv;
    __syncthreads();
    bf16x8 a0 = *(const bf16x8*)&As[wr + c][g * 8];
    bf16x8 a1 = *(const bf16x8*)&As[wr + 16 + c][g * 8];
    bf16x8 b0 = *(const bf16x8*)&Bs[wc + c][g * 8];
    bf16x8 b1 = *(const bf16x8*)&Bs[wc + 16 + c][g * 8];
    acc[0][0] = __builtin_amdgcn_mfma_f32_16x16x32_bf16(a0, b0, acc[0][0], 0, 0, 0);
    acc[0][1] = __builtin_amdgcn_mfma_f32_16x16x32_bf16(a0, b1, acc[0][1], 0, 0, 0);
    acc[1][0] = __builtin_amdgcn_mfma_f32_16x16x32_bf16(a1, b0, acc[1][0], 0, 0, 0);
    acc[1][1] = __builtin_amdgcn_mfma_f32_16x16x32_bf16(a1, b1, acc[1][1], 0, 0, 0);
    __syncthreads();
  }
  for (int fm = 0; fm < 2; ++fm)
    for (int fn = 0; fn < 2; ++fn)
      for (int r = 0; r < 4; ++r) {
        int row = m0 + wr + fm * 16 + g * 4 + r;
        int col = n0 + wc + fn * 16 + c;
        float v = acc[fm][fn][r] + bias[col];
        if constexpr (OUT_BF16) ((u16*)Cout)[(size_t)row * ldc + col] = f2bf(v);
        else                    ((float*)Cout)[(size_t)row * ldc + col] = v;
      }
}

// Barrier-free attention: 4 independent waves/block, each owns 16 q-rows.
// K and V fragments loaded directly from global (Vtb is pre-transposed).
// grid (16 qt, 10 units, 4 b).
__global__ __launch_bounds__(256) void attn_k(
    const u16* __restrict__ P, const u16* __restrict__ Vtb, u16* __restrict__ Y,
    const float* __restrict__ mix_w, const float* __restrict__ bias_clip,
    const float* __restrict__ bias_clip_ml) {
  __shared__ u16 Ps[4][16][72];
  const int tid = threadIdx.x, lane = tid & 63, w = tid >> 6;
  const int g = lane >> 4, c = lane & 15;
  const int qt = blockIdx.x, u = blockIdx.y, b = blockIdx.z;

  int qcol, kcol, vsel, outcol;
  bool localMask;
  float kbias, wgt;
  if (u < 8) {
    qcol = u * 64; kcol = 512 + u * 64; vsel = u; outcol = u * 64;
    localMask = (u < 2);
    kbias = bias_clip[u];
    wgt = (u == 2 || u == 3) ? mix_w[(u - 2) * 2] : 1.0f;
  } else {
    int mh = u - 8;
    qcol = 1024 + mh * 64; kcol = 1152 + mh * 64; vsel = 2 + mh; outcol = 512 + mh * 64;
    localMask = true;
    kbias = bias_clip_ml[mh];
    wgt = mix_w[mh * 2 + 1];
  }
  const size_t baseP = (size_t)b * T_SEQ * PROJW;
  const u16* __restrict__ Vbase = Vtb + ((size_t)b * 512 + vsel * 64) * 1024;

  const int r0 = qt * 64 + w * 16, r1 = r0 + 15;

  // ---- exact per-wave kv-tile mask (split at the 512/513 temporal boundary) ----
  unsigned mask = 1u;
  {
    auto addRange = [&](int colA, int colB) {
      int ta = colA >> 6, tb = colB >> 6;
      mask |= ((2u << tb) - 1) & ~((1u << ta) - 1);
    };
    int a = r0 < 2 ? 2 : r0;
    int bU = r1 < 513 ? r1 : 512;
    if (a <= bU) {  // upper-half rows
      int jqa = a - 2, jqb = bU - 2;
      int wmn = localMask ? (jqa - 3 > 0 ? jqa - 3 : 0) : 0;
      addRange(2 + wmn, 2 + jqb);
      if (jqb - 1 >= wmn) addRange(513 + wmn, 513 + jqb - 1);
    }
    if (r1 >= 513) {  // lower-half rows
      int a2 = r0 > 513 ? r0 : 513;
      int jqa = a2 - 513, jqb = r1 - 513;
      int wmn = localMask ? (jqa - 3 > 0 ? jqa - 3 : 0) : 0;
      addRange(2 + wmn, 2 + jqb);
      addRange(513 + wmn, 513 + jqb);
    }
  }

  // ---- per-row visibility bounds (rows r0 + g*4 + r) ----
  int upmax[4], lomax[4], wminr[4];
#pragma unroll
  for (int r = 0; r < 4; ++r) {
    int row = r0 + g * 4 + r;
    int tqr = (row < 2) ? 0 : ((row < 513) ? 2 * row - 3 : 2 * row - 1024);
    upmax[r] = (tqr - 1) >> 1;
    lomax[r] = (tqr - 2) >> 1;
    wminr[r] = (localMask && row >= 2) ? ((row < 513 ? row - 2 : row - 513) - 3) : -1000000;
  }

  // Q fragment (rows r0+c)
  const int qrow = r0 + c;
  bf16x8 aq0 = *(const bf16x8*)&P[baseP + (size_t)qrow * PROJW + qcol + g * 8];
  bf16x8 aq1 = *(const bf16x8*)&P[baseP + (size_t)qrow * PROJW + qcol + 32 + g * 8];

  float m[4], l[4];
  f32x4 o[4] = {};
#pragma unroll
  for (int r = 0; r < 4; ++r) { m[r] = -1e30f; l[r] = 0.0f; }

  bf16x8 kr0[4], kr1[4];
  unsigned rem = mask;
  int kt = __ffs(rem) - 1; rem &= rem - 1;
#pragma unroll
  for (int cb = 0; cb < 4; ++cb) {
    const u16* ks = &P[baseP + (size_t)(kt * 64 + cb * 16 + c) * PROJW + kcol + g * 8];
    kr0[cb] = *(const bf16x8*)ks;
    kr1[cb] = *(const bf16x8*)(ks + 32);
  }

  while (true) {
    int ktn = -1;
    if (rem) { ktn = __ffs(rem) - 1; rem &= rem - 1; }
    const int k0 = kt * 64;

    // V fragments for current tile (consumed after softmax -> latency hidden)
    bf16x8 vr[2][4];
#pragma unroll
    for (int ks2 = 0; ks2 < 2; ++ks2)
#pragma unroll
      for (int db = 0; db < 4; ++db)
        vr[ks2][db] = *(const bf16x8*)&Vbase[(size_t)(db * 16 + c) * 1024 + k0 + ks2 * 32 + g * 8];

    // QK^T
    float s[4][4];
#pragma unroll
    for (int cb = 0; cb < 4; ++cb) {
      f32x4 accs = {};
      accs = __builtin_amdgcn_mfma_f32_16x16x32_bf16(aq0, kr0[cb], accs, 0, 0, 0);
      accs = __builtin_amdgcn_mfma_f32_16x16x32_bf16(aq1, kr1[cb], accs, 0, 0, 0);
#pragma unroll
      for (int r = 0; r < 4; ++r) s[cb][r] = accs[r] * 0.125f;
    }

    // prefetch K for next tile into the now-dead kr registers
    if (ktn >= 0) {
#pragma unroll
      for (int cb = 0; cb < 4; ++cb) {
        const u16* ks = &P[baseP + (size_t)(ktn * 64 + cb * 16 + c) * PROJW + kcol + g * 8];
        kr0[cb] = *(const bf16x8*)ks;
        kr1[cb] = *(const bf16x8*)(ks + 32);
      }
    }

    // mask + bias (bound compares, no full temporal recompute)
#pragma unroll
    for (int cb = 0; cb < 4; ++cb) {
      int colg = k0 + cb * 16 + c;
      bool tok = colg < 2;
      bool low = colg >= 513;
      int jk = colg - (low ? 513 : 2);
      float addb = (colg == 1) ? kbias : 0.0f;
#pragma unroll
      for (int r = 0; r < 4; ++r) {
        int bnd = low ? lomax[r] : upmax[r];
        bool vis = tok | ((jk <= bnd) & (jk >= wminr[r]));
        s[cb][r] = vis ? (s[cb][r] + addb) : -1e9f;
      }
    }

    // online softmax (reduce over the 16 c-lanes)
#pragma unroll
    for (int r = 0; r < 4; ++r) {
      float rmax = fmaxf(fmaxf(s[0][r], s[1][r]), fmaxf(s[2][r], s[3][r]));
      for (int off = 1; off < 16; off <<= 1)
        rmax = fmaxf(rmax, __shfl_xor(rmax, off));
      float mnew = fmaxf(m[r], rmax);
      float fr = __expf(m[r] - mnew);
      float psum = 0.0f;
#pragma unroll
      for (int cb = 0; cb < 4; ++cb) {
        float p = __expf(s[cb][r] - mnew);
        s[cb][r] = p;
        psum += p;
      }
      for (int off = 1; off < 16; off <<= 1)
        psum += __shfl_xor(psum, off);
      l[r] = l[r] * fr + psum;
      m[r] = mnew;
#pragma unroll
      for (int db = 0; db < 4; ++db) o[db][r] *= fr;
    }

    // P bounce through per-wave LDS slice (no cross-wave sync needed)
#pragma unroll
    for (int cb = 0; cb < 4; ++cb)
#pragma unroll
      for (int r = 0; r < 4; ++r)
        Ps[w][g * 4 + r][cb * 16 + c] = f2bf(s[cb][r]);

#pragma unroll
    for (int ks2 = 0; ks2 < 2; ++ks2) {
      bf16x8 ap = *(const bf16x8*)&Ps[w][c][ks2 * 32 + g * 8];
#pragma unroll
      for (int db = 0; db < 4; ++db)
        o[db] = __builtin_amdgcn_mfma_f32_16x16x32_bf16(ap, vr[ks2][db], o[db], 0, 0, 0);
    }

    if (ktn < 0) break;
    kt = ktn;
  }

  float wl[4];
#pragma unroll
  for (int r = 0; r < 4; ++r) wl[r] = wgt / l[r];
#pragma unroll
  for (int db = 0; db < 4; ++db)
#pragma unroll
    for (int r = 0; r < 4; ++r) {
      int row = r0 + g * 4 + r;
      int col = outcol + db * 16 + c;
      Y[((size_t)b * T_SEQ + row) * 640 + col] = f2bf(o[db][r] * wl[r]);
    }
}

extern "C" void kernel_launch(void* const* d_in, const int* in_sizes, int n_in,
                              void* d_out, int out_size, void* d_ws, size_t ws_size,
                              hipStream_t stream) {
  const float* x     = (const float*)d_in[0];
  const float* Wq    = (const float*)d_in[2];
  const float* bq    = (const float*)d_in[3];
  const float* Wk    = (const float*)d_in[4];
  const float* bk    = (const float*)d_in[5];
  const float* Wv    = (const float*)d_in[6];
  const float* bv    = (const float*)d_in[7];
  const float* Wqml  = (const float*)d_in[8];
  const float* bqml  = (const float*)d_in[9];
  const float* Wkml  = (const float*)d_in[10];
  const float* bkml  = (const float*)d_in[11];
  const float* mixw  = (const float*)d_in[12];
  const float* Wp    = (const float*)d_in[13];
  const float* bp    = (const float*)d_in[14];
  const float* bclip = (const float*)d_in[15];
  const float* bclipml = (const float*)d_in[16];

  u16* xb   = (u16*)d_ws;                  // 4096*512
  u16* Wcat = xb + 4096 * 512;             // 1792*512
  u16* Wpx  = Wcat + 1792 * 512;           // 512*640
  u16* Ybuf = Wpx + 512 * 640;             // 4096*640
  u16* Vtb  = Ybuf + 4096 * 640;           // 4*512*1024
  u16* Pbuf = Vtb + 4 * 512 * 1024;        // 4096*1280
  float* bcat = (float*)(Pbuf + 4096 * 1280);  // 1792 f32

  prep_all<<<6919, 256, 0, stream>>>((const float4*)x, xb, Wq, Wk, Wv, Wqml, Wkml, Wp,
                                     bq, bk, bv, bqml, bkml, Wcat, Wpx, bcat);
  gemm_qkv<<<dim3(28, 64), 256, 0, stream>>>(xb, Wcat, bcat, Pbuf, Vtb);
  attn_k<<<dim3(16, 10, 4), 256, 0, stream>>>(Pbuf, Vtb, Ybuf, mixw, bclip, bclipml);
  gemm_bt<false><<<dim3(8, 64), 256, 0, stream>>>(Ybuf, 640, Wpx, 640, bp,
                                                  (void*)d_out, 512, 640);
}

// Round 4
// 88.228 us; speedup vs baseline: 1.2903x; 1.2903x over previous
//
#include <hip/hip_runtime.h>

typedef unsigned short u16;
typedef __attribute__((ext_vector_type(8))) __bf16 bf16x8;
typedef __attribute__((ext_vector_type(4))) float f32x4;
typedef __attribute__((ext_vector_type(8))) short short8;
typedef __attribute__((ext_vector_type(4))) u16 us4;

#define T_SEQ 1024
#define PW 1280   // P row: Q(512) K(512) QML(128) KML(128); V lives in Vtb

__device__ __forceinline__ u16 f2bf(float f) {
  unsigned u = __float_as_uint(f);
  u += 0x7fff + ((u >> 16) & 1);
  return (u16)(u >> 16);
}

// exact per-qtile kv-tile occupancy masks (derived from interleaved temporal
// causal order + RECEP=4 window); verified in round 2.
__constant__ u16 GLOB_M[16] = {0x0101,0x0303,0x0707,0x0F0F,0x1F1F,0x3F3F,0x7F7F,0xFFFF,
                               0xFFFF,0x0307,0x070F,0x0F1F,0x1F3F,0x3F7F,0x7FFF,0xFFFF};
__constant__ u16 LOC_M[16]  = {0x0101,0x0303,0x0607,0x0C0D,0x1819,0x3031,0x6061,0xC0C1,
                               0x8183,0x0307,0x060F,0x0C1D,0x1839,0x3071,0x60E1,0xC1C1};

__global__ void prep_all(const float4* __restrict__ x, u16* __restrict__ xb,
                         const float* __restrict__ Wq, const float* __restrict__ Wk,
                         const float* __restrict__ Wv, const float* __restrict__ Wqml,
                         const float* __restrict__ Wkml, const float* __restrict__ Wp,
                         const float* __restrict__ bq, const float* __restrict__ bk,
                         const float* __restrict__ bv, const float* __restrict__ bqml,
                         const float* __restrict__ bkml,
                         u16* __restrict__ Wcat, u16* __restrict__ Wpx, float* __restrict__ bcat) {
  if (blockIdx.x < 2048) {
    int i = blockIdx.x * 256 + threadIdx.x;
    float4 v = x[i];
    us4 o = { f2bf(v.x), f2bf(v.y), f2bf(v.z), f2bf(v.w) };
    *(us4*)&xb[i * 4] = o;
    return;
  }
  int idx = (blockIdx.x - 2048) * 256 + threadIdx.x;
  const int NW = 1792 * 512;
  if (idx < NW) {
    int row = idx >> 9;
    float v;
    if (row < 512)       v = Wq[idx];
    else if (row < 1024) v = Wk[idx - 512 * 512];
    else if (row < 1536) v = Wv[idx - 1024 * 512];
    else if (row < 1664) v = Wqml[idx - 1536 * 512];
    else                 v = Wkml[idx - 1664 * 512];
    Wcat[idx] = f2bf(v);
    return;
  }
  int i2 = idx - NW;
  if (i2 < 512 * 640) {
    int n = i2 / 640, k2 = i2 - n * 640;
    float v = (k2 < 512) ? Wp[n * 512 + k2] : Wp[n * 512 + k2 - 384];
    Wpx[i2] = f2bf(v);
    return;
  }
  int i3 = i2 - 512 * 640;
  if (i3 < 1792) {
    float v;
    if (i3 < 512)       v = bq[i3];
    else if (i3 < 1024) v = bk[i3 - 512];
    else if (i3 < 1536) v = bv[i3 - 1024];
    else if (i3 < 1664) v = bqml[i3 - 1536];
    else                v = bkml[i3 - 1664];
    bcat[i3] = v;
  }
}

// ---------------- 128x128 QKV projection GEMM (m97 structure) ----------------
// C = x @ Wcat^T + bias. Q,K,QML,KML -> Pout; V cols (1024..1535) -> Vtb^T.

__device__ __forceinline__ void stage64(const u16* __restrict__ G, int row0,
                                        u16* lbase, int t, int w) {
#pragma unroll
  for (int j = 0; j < 2; ++j) {
    const u16* gp = &G[(size_t)(row0 + j * 64 + (t >> 2)) * 512 + (t & 3) * 8];
    u16* lp = lbase + j * 2048 + w * 512;
    __builtin_amdgcn_global_load_lds((const __attribute__((address_space(1))) unsigned*)gp,
                                     (__attribute__((address_space(3))) unsigned*)lp,
                                     16, 0, 0);
  }
}

__global__ __launch_bounds__(256) void gemm_qkv(
    const u16* __restrict__ A, const u16* __restrict__ Bw,
    const float* __restrict__ bias, u16* __restrict__ Pout, u16* __restrict__ Vtb) {
  __shared__ u16 As[2][4096];
  __shared__ u16 Bs[2][4096];
  const int tid = threadIdx.x;
  const int lane = tid & 63, w = tid >> 6;
  const int g = lane >> 4, c = lane & 15;
  const int n0 = blockIdx.x * 128, m0 = blockIdx.y * 128;
  const int wm = (w >> 1) * 64, wn = (w & 1) * 64;

  f32x4 acc[4][4] = {};
  stage64(&A[(size_t)m0 * 512], 0, As[0], tid, w);
  stage64(&Bw[(size_t)n0 * 512], 0, Bs[0], tid, w);
  __syncthreads();
  for (int ks = 0; ks < 16; ++ks) {
    int cur = ks & 1;
    if (ks + 1 < 16) {
      stage64(&A[(size_t)m0 * 512 + (ks + 1) * 32], 0, As[cur ^ 1], tid, w);
      stage64(&Bw[(size_t)n0 * 512 + (ks + 1) * 32], 0, Bs[cur ^ 1], tid, w);
    }
    bf16x8 av[4], bv[4];
#pragma unroll
    for (int f = 0; f < 4; ++f) {
      av[f] = *(const bf16x8*)&As[cur][(wm + f * 16 + c) * 32 + g * 8];
      bv[f] = *(const bf16x8*)&Bs[cur][(wn + f * 16 + c) * 32 + g * 8];
    }
#pragma unroll
    for (int fm = 0; fm < 4; ++fm)
#pragma unroll
      for (int fn = 0; fn < 4; ++fn)
        acc[fm][fn] = __builtin_amdgcn_mfma_f32_16x16x32_bf16(av[fm], bv[fn], acc[fm][fn], 0, 0, 0);
    __syncthreads();
  }

  const bool isV = (n0 >= 1024 && n0 < 1536);
#pragma unroll
  for (int fm = 0; fm < 4; ++fm)
#pragma unroll
    for (int fn = 0; fn < 4; ++fn) {
      int row = m0 + wm + fm * 16 + g * 4;
      int col = n0 + wn + fn * 16 + c;
      float bb = bias[col];
      if (isV) {
        int d = col - 1024;
        int bidx = row >> 10, t = row & 1023;
        us4 pack = { f2bf(acc[fm][fn][0] + bb), f2bf(acc[fm][fn][1] + bb),
                     f2bf(acc[fm][fn][2] + bb), f2bf(acc[fm][fn][3] + bb) };
        *(us4*)&Vtb[((size_t)bidx * 512 + d) * 1024 + t] = pack;
      } else {
        int pcol = (col < 1024) ? col : col - 512;
#pragma unroll
        for (int r = 0; r < 4; ++r)
          Pout[(size_t)(row + r) * PW + pcol] = f2bf(acc[fm][fn][r] + bb);
      }
    }
}

// ---------------- generic 64x64 GEMM (output projection) ----------------
template<bool OUT_BF16>
__global__ __launch_bounds__(256) void gemm_bt(
    const u16* __restrict__ A, int lda,
    const u16* __restrict__ Bw, int ldb,
    const float* __restrict__ bias,
    void* __restrict__ Cout, int ldc, int K) {
  __shared__ u16 As[64][40];
  __shared__ u16 Bs[64][40];
  const int tid = threadIdx.x;
  const int lane = tid & 63, w = tid >> 6;
  const int g = lane >> 4, c = lane & 15;
  const int m0 = blockIdx.y * 64, n0 = blockIdx.x * 64;
  const int wr = (w >> 1) * 32, wc = (w & 1) * 32;
  const int arow = tid >> 2, acol = (tid & 3) * 8;

  f32x4 acc[2][2] = {};
  for (int k0 = 0; k0 < K; k0 += 32) {
    short8 av = *(const short8*)&A[(size_t)(m0 + arow) * lda + k0 + acol];
    short8 bv = *(const short8*)&Bw[(size_t)(n0 + arow) * ldb + k0 + acol];
    *(short8*)&As[arow][acol] = av;
    *(short8*)&Bs[arow][acol] = bv;
    __syncthreads();
    bf16x8 a0 = *(const bf16x8*)&As[wr + c][g * 8];
    bf16x8 a1 = *(const bf16x8*)&As[wr + 16 + c][g * 8];
    bf16x8 b0 = *(const bf16x8*)&Bs[wc + c][g * 8];
    bf16x8 b1 = *(const bf16x8*)&Bs[wc + 16 + c][g * 8];
    acc[0][0] = __builtin_amdgcn_mfma_f32_16x16x32_bf16(a0, b0, acc[0][0], 0, 0, 0);
    acc[0][1] = __builtin_amdgcn_mfma_f32_16x16x32_bf16(a0, b1, acc[0][1], 0, 0, 0);
    acc[1][0] = __builtin_amdgcn_mfma_f32_16x16x32_bf16(a1, b0, acc[1][0], 0, 0, 0);
    acc[1][1] = __builtin_amdgcn_mfma_f32_16x16x32_bf16(a1, b1, acc[1][1], 0, 0, 0);
    __syncthreads();
  }
  for (int fm = 0; fm < 2; ++fm)
    for (int fn = 0; fn < 2; ++fn)
      for (int r = 0; r < 4; ++r) {
        int row = m0 + wr + fm * 16 + g * 4 + r;
        int col = n0 + wc + fn * 16 + c;
        float v = acc[fm][fn][r] + bias[col];
        if constexpr (OUT_BF16) ((u16*)Cout)[(size_t)row * ldc + col] = f2bf(v);
        else                    ((float*)Cout)[(size_t)row * ldc + col] = v;
      }
}

// ---------------- attention ----------------
// grid (16 qt, 16 units, 4 b). units: 0,1 local heads (direct); 2..13 causal
// heads 2..7 split even/odd kv-tiles (partials -> Part); 14,15 ml local (direct).
__global__ __launch_bounds__(256) void attn_k(
    const u16* __restrict__ P, const u16* __restrict__ Vtb, u16* __restrict__ Y,
    float* __restrict__ Part,
    const float* __restrict__ mix_w, const float* __restrict__ bias_clip,
    const float* __restrict__ bias_clip_ml) {
  __shared__ u16 Ks[64][72];
  __shared__ u16 Vs[64][72];
  __shared__ u16 Ps[4][16][72];
  const int tid = threadIdx.x, lane = tid & 63, w = tid >> 6;
  const int g = lane >> 4, c = lane & 15;
  const int qt = blockIdx.x, u = blockIdx.y, b = blockIdx.z;

  int qcol, kcol, vsel, outcol = 0, hp = 0, sp = 0;
  bool localMask = false, split = false;
  float kbias, wgt = 1.0f;
  if (u < 2) {
    qcol = u * 64; kcol = 512 + u * 64; vsel = u; outcol = u * 64;
    localMask = true; kbias = bias_clip[u];
  } else if (u < 14) {
    int h = 2 + ((u - 2) >> 1); sp = (u - 2) & 1; split = true; hp = h - 2;
    qcol = h * 64; kcol = 512 + h * 64; vsel = h; kbias = bias_clip[h];
  } else {
    int mh = u - 14;
    qcol = 1024 + mh * 64; kcol = 1152 + mh * 64; vsel = 2 + mh; outcol = 512 + mh * 64;
    localMask = true; kbias = bias_clip_ml[mh]; wgt = mix_w[mh * 2 + 1];
  }
  unsigned mask = localMask ? (unsigned)LOC_M[qt] : (unsigned)GLOB_M[qt];
  if (split) mask &= sp ? 0xAAAAu : 0x5555u;

  const size_t baseP = (size_t)b * T_SEQ * PW;
  const u16* __restrict__ Vbase = Vtb + ((size_t)b * 512 + vsel * 64) * 1024;
  const int r0 = qt * 64 + w * 16;
  const int srow = tid >> 2, scol = (tid & 3) * 16;

  // per-row visibility bounds
  int upmax[4], lomax[4], wminr[4];
#pragma unroll
  for (int r = 0; r < 4; ++r) {
    int row = r0 + g * 4 + r;
    int tqr = (row < 2) ? 0 : ((row < 513) ? 2 * row - 3 : 2 * row - 1024);
    upmax[r] = (tqr - 1) >> 1;
    lomax[r] = (tqr - 2) >> 1;
    wminr[r] = (localMask && row >= 2) ? ((row < 513 ? row - 2 : row - 513) - 3) : -1000000;
  }

  float m[4], l[4];
  f32x4 o[4] = {};
#pragma unroll
  for (int r = 0; r < 4; ++r) { m[r] = -1e8f; l[r] = 0.0f; }

  if (mask) {
    const int qrow = r0 + c;
    bf16x8 aq0 = *(const bf16x8*)&P[baseP + (size_t)qrow * PW + qcol + g * 8];
    bf16x8 aq1 = *(const bf16x8*)&P[baseP + (size_t)qrow * PW + qcol + 32 + g * 8];

    unsigned rem = mask;
    int kt = __ffs(rem) - 1; rem &= rem - 1;
    short8 ka, kb2, va, vb2;
    {
      const u16* kp = &P[baseP + (size_t)(kt * 64 + srow) * PW + kcol + scol];
      ka = *(const short8*)kp; kb2 = *(const short8*)(kp + 8);
      const u16* vp = &Vbase[(size_t)srow * 1024 + kt * 64 + scol];
      va = *(const short8*)vp; vb2 = *(const short8*)(vp + 8);
    }

    for (;;) {
      __syncthreads();
      *(short8*)&Ks[srow][scol] = ka;
      *(short8*)&Ks[srow][scol + 8] = kb2;
      *(short8*)&Vs[srow][scol] = va;
      *(short8*)&Vs[srow][scol + 8] = vb2;
      __syncthreads();

      int ktn = -1;
      if (rem) {
        ktn = __ffs(rem) - 1; rem &= rem - 1;
        const u16* kp = &P[baseP + (size_t)(ktn * 64 + srow) * PW + kcol + scol];
        ka = *(const short8*)kp; kb2 = *(const short8*)(kp + 8);
        const u16* vp = &Vbase[(size_t)srow * 1024 + ktn * 64 + scol];
        va = *(const short8*)vp; vb2 = *(const short8*)(vp + 8);
      }

      const int k0 = kt * 64;
      float s[4][4];
#pragma unroll
      for (int cb = 0; cb < 4; ++cb) {
        f32x4 accs = {};
        bf16x8 bk0 = *(const bf16x8*)&Ks[cb * 16 + c][g * 8];
        bf16x8 bk1 = *(const bf16x8*)&Ks[cb * 16 + c][32 + g * 8];
        accs = __builtin_amdgcn_mfma_f32_16x16x32_bf16(aq0, bk0, accs, 0, 0, 0);
        accs = __builtin_amdgcn_mfma_f32_16x16x32_bf16(aq1, bk1, accs, 0, 0, 0);
#pragma unroll
        for (int r = 0; r < 4; ++r) s[cb][r] = accs[r] * 0.125f;
      }
#pragma unroll
      for (int cb = 0; cb < 4; ++cb) {
        int colg = k0 + cb * 16 + c;
        bool tok = colg < 2;
        bool low = colg >= 513;
        int jk = colg - (low ? 513 : 2);
        float addb = (colg == 1) ? kbias : 0.0f;
#pragma unroll
        for (int r = 0; r < 4; ++r) {
          int bnd = low ? lomax[r] : upmax[r];
          bool vis = tok | ((jk <= bnd) & (jk >= wminr[r]));
          s[cb][r] = vis ? (s[cb][r] + addb) : -1e9f;
        }
      }
#pragma unroll
      for (int r = 0; r < 4; ++r) {
        float rmax = fmaxf(fmaxf(s[0][r], s[1][r]), fmaxf(s[2][r], s[3][r]));
        for (int off = 1; off < 16; off <<= 1)
          rmax = fmaxf(rmax, __shfl_xor(rmax, off));
        float mnew = fmaxf(m[r], rmax);
        float fr = __expf(m[r] - mnew);
        float psum = 0.0f;
#pragma unroll
        for (int cb = 0; cb < 4; ++cb) {
          float p = __expf(s[cb][r] - mnew);
          s[cb][r] = p;
          psum += p;
        }
        for (int off = 1; off < 16; off <<= 1)
          psum += __shfl_xor(psum, off);
        l[r] = l[r] * fr + psum;
        m[r] = mnew;
#pragma unroll
        for (int db = 0; db < 4; ++db) o[db][r] *= fr;
      }
#pragma unroll
      for (int cb = 0; cb < 4; ++cb)
#pragma unroll
        for (int r = 0; r < 4; ++r)
          Ps[w][g * 4 + r][cb * 16 + c] = f2bf(s[cb][r]);
      asm volatile("s_waitcnt lgkmcnt(0)" ::: "memory");
      __builtin_amdgcn_sched_barrier(0);
#pragma unroll
      for (int ks2 = 0; ks2 < 2; ++ks2) {
        bf16x8 ap = *(const bf16x8*)&Ps[w][c][ks2 * 32 + g * 8];
#pragma unroll
        for (int db = 0; db < 4; ++db) {
          bf16x8 bv = *(const bf16x8*)&Vs[db * 16 + c][ks2 * 32 + g * 8];
          o[db] = __builtin_amdgcn_mfma_f32_16x16x32_bf16(ap, bv, o[db], 0, 0, 0);
        }
      }
      if (ktn < 0) break;
      kt = ktn;
    }
  }

  if (split) {
    float* pb = Part + (size_t)((hp * 2 + sp) * 4 + b) * T_SEQ * 68;
#pragma unroll
    for (int r = 0; r < 4; ++r) {
      int row = r0 + g * 4 + r;
#pragma unroll
      for (int db = 0; db < 4; ++db)
        pb[(size_t)row * 68 + db * 16 + c] = o[db][r];
      if (c == 0) {
        pb[(size_t)row * 68 + 64] = m[r];
        pb[(size_t)row * 68 + 65] = l[r];
      }
    }
  } else {
    float wl[4];
#pragma unroll
    for (int r = 0; r < 4; ++r) wl[r] = wgt / l[r];
#pragma unroll
    for (int db = 0; db < 4; ++db)
#pragma unroll
      for (int r = 0; r < 4; ++r) {
        int row = r0 + g * 4 + r;
        int col = outcol + db * 16 + c;
        Y[((size_t)b * T_SEQ + row) * 640 + col] = f2bf(o[db][r] * wl[r]);
      }
  }
}

// combine split-K partials for heads 2..7 -> Y cols 128..511
__global__ __launch_bounds__(256) void combine_k(
    const float* __restrict__ Part, u16* __restrict__ Y,
    const float* __restrict__ mix_w) {
  int idx = blockIdx.x * 256 + threadIdx.x;  // 6*4*1024*16
  int q4 = idx & 15;
  int row = (idx >> 4) & 1023;
  int hb = idx >> 14;
  int hp = hb >> 2, b = hb & 3;
  const float* p1 = Part + ((size_t)((hp * 2 + 0) * 4 + b) * 1024 + row) * 68;
  const float* p2 = Part + ((size_t)((hp * 2 + 1) * 4 + b) * 1024 + row) * 68;
  float m1 = p1[64], l1 = p1[65];
  float m2 = p2[64], l2 = p2[65];
  float ms = fmaxf(m1, m2);
  float e1 = __expf(m1 - ms), e2 = __expf(m2 - ms);
  float wgt = (hp < 2) ? mix_w[hp * 2] : 1.0f;
  float inv = wgt / (l1 * e1 + l2 * e2);
  float4 o1 = *(const float4*)&p1[q4 * 4];
  float4 o2 = *(const float4*)&p2[q4 * 4];
  us4 pack = { f2bf((o1.x * e1 + o2.x * e2) * inv),
               f2bf((o1.y * e1 + o2.y * e2) * inv),
               f2bf((o1.z * e1 + o2.z * e2) * inv),
               f2bf((o1.w * e1 + o2.w * e2) * inv) };
  *(us4*)&Y[((size_t)b * 1024 + row) * 640 + (hp + 2) * 64 + q4 * 4] = pack;
}

extern "C" void kernel_launch(void* const* d_in, const int* in_sizes, int n_in,
                              void* d_out, int out_size, void* d_ws, size_t ws_size,
                              hipStream_t stream) {
  const float* x     = (const float*)d_in[0];
  const float* Wq    = (const float*)d_in[2];
  const float* bq    = (const float*)d_in[3];
  const float* Wk    = (const float*)d_in[4];
  const float* bk    = (const float*)d_in[5];
  const float* Wv    = (const float*)d_in[6];
  const float* bv    = (const float*)d_in[7];
  const float* Wqml  = (const float*)d_in[8];
  const float* bqml  = (const float*)d_in[9];
  const float* Wkml  = (const float*)d_in[10];
  const float* bkml  = (const float*)d_in[11];
  const float* mixw  = (const float*)d_in[12];
  const float* Wp    = (const float*)d_in[13];
  const float* bp    = (const float*)d_in[14];
  const float* bclip = (const float*)d_in[15];
  const float* bclipml = (const float*)d_in[16];

  u16* xb   = (u16*)d_ws;                  // 4096*512
  u16* Wcat = xb + 4096 * 512;             // 1792*512
  u16* Wpx  = Wcat + 1792 * 512;           // 512*640
  u16* Ybuf = Wpx + 512 * 640;             // 4096*640
  u16* Vtb  = Ybuf + 4096 * 640;           // 4*512*1024
  u16* Pbuf = Vtb + 4 * 512 * 1024;        // 4096*1280
  float* bcat = (float*)(Pbuf + 4096 * 1280);  // 1792 f32 (pad 2048)
  float* Part = bcat + 2048;               // 48*1024*68 f32 = 13.4 MB

  prep_all<<<6919, 256, 0, stream>>>((const float4*)x, xb, Wq, Wk, Wv, Wqml, Wkml, Wp,
                                     bq, bk, bv, bqml, bkml, Wcat, Wpx, bcat);
  gemm_qkv<<<dim3(14, 32), 256, 0, stream>>>(xb, Wcat, bcat, Pbuf, Vtb);
  attn_k<<<dim3(16, 16, 4), 256, 0, stream>>>(Pbuf, Vtb, Ybuf, Part, mixw, bclip, bclipml);
  combine_k<<<1536, 256, 0, stream>>>(Part, Ybuf, mixw);
  gemm_bt<false><<<dim3(8, 64), 256, 0, stream>>>(Ybuf, 640, Wpx, 640, bp,
                                                  (void*)d_out, 512, 640);
}

// Round 5
// 83.665 us; speedup vs baseline: 1.3606x; 1.0545x over previous
//
#include <hip/hip_runtime.h>

typedef unsigned short u16;
typedef __attribute__((ext_vector_type(8))) __bf16 bf16x8;
typedef __attribute__((ext_vector_type(4))) float f32x4;
typedef __attribute__((ext_vector_type(8))) short short8;
typedef __attribute__((ext_vector_type(4))) u16 us4;

#define T_SEQ 1024
#define PW 1280   // P row: Q(512) K(512) QML(128) KML(128); V lives in Vtb

__device__ __forceinline__ u16 f2bf(float f) {
  unsigned u = __float_as_uint(f);
  u += 0x7fff + ((u >> 16) & 1);
  return (u16)(u >> 16);
}
__device__ __forceinline__ float bf2f(u16 v) {
  return __uint_as_float((unsigned)v << 16);
}

// exact per-qtile kv-tile occupancy masks (verified rounds 2-4)
__constant__ u16 GLOB_M[16] = {0x0101,0x0303,0x0707,0x0F0F,0x1F1F,0x3F3F,0x7F7F,0xFFFF,
                               0xFFFF,0x0307,0x070F,0x0F1F,0x1F3F,0x3F7F,0x7FFF,0xFFFF};
__constant__ u16 LOC_M[16]  = {0x0101,0x0303,0x0607,0x0C0D,0x1819,0x3031,0x6061,0xC0C1,
                               0x8183,0x0307,0x060F,0x0C1D,0x1839,0x3071,0x60E1,0xC1C1};

__device__ __forceinline__ void gll16(const u16* gp, u16* lp) {
  __builtin_amdgcn_global_load_lds((const __attribute__((address_space(1))) unsigned*)gp,
                                   (__attribute__((address_space(3))) unsigned*)lp, 16, 0, 0);
}

// Stage NISS*32 rows x 64 cols (bf16) of G (row stride ld elems) into LDS,
// linear dest, inverse-swizzled source: LDS linear slot (row, cb) holds
// G[row][ (cb ^ ((row&7)<<4)) ]  (cb = byte col). 256 threads.
template<int NISS>
__device__ __forceinline__ void stage_sw(u16* lds, const u16* __restrict__ g,
                                         int ld, int tid) {
  const int w = tid >> 6;
#pragma unroll
  for (int i = 0; i < NISS; ++i) {
    int row = i * 32 + (tid >> 3);
    int cswz = ((tid & 7) << 4) ^ ((row & 7) << 4);
    gll16(g + (size_t)row * ld + (cswz >> 1), lds + i * 2048 + w * 512);
  }
}

// read a bf16x8 fragment at logical (row, colbyte) from a swizzled 64-col tile
__device__ __forceinline__ bf16x8 rd_sw(const u16* lds, int row, int colbyte) {
  return *(const bf16x8*)&lds[row * 64 + ((colbyte ^ ((row & 7) << 4)) >> 1)];
}

__global__ void prep_all(const float4* __restrict__ x, u16* __restrict__ xb,
                         const float* __restrict__ Wq, const float* __restrict__ Wk,
                         const float* __restrict__ Wv, const float* __restrict__ Wqml,
                         const float* __restrict__ Wkml, const float* __restrict__ Wp,
                         const float* __restrict__ bq, const float* __restrict__ bk,
                         const float* __restrict__ bv, const float* __restrict__ bqml,
                         const float* __restrict__ bkml,
                         u16* __restrict__ Wcat, u16* __restrict__ Wpx, float* __restrict__ bcat) {
  if (blockIdx.x < 2048) {
    int i = blockIdx.x * 256 + threadIdx.x;
    float4 v = x[i];
    us4 o = { f2bf(v.x), f2bf(v.y), f2bf(v.z), f2bf(v.w) };
    *(us4*)&xb[i * 4] = o;
    return;
  }
  int idx = (blockIdx.x - 2048) * 256 + threadIdx.x;
  const int NW = 1792 * 512;
  if (idx < NW) {
    int row = idx >> 9;
    float v;
    if (row < 512)       v = Wq[idx];
    else if (row < 1024) v = Wk[idx - 512 * 512];
    else if (row < 1536) v = Wv[idx - 1024 * 512];
    else if (row < 1664) v = Wqml[idx - 1536 * 512];
    else                 v = Wkml[idx - 1664 * 512];
    Wcat[idx] = f2bf(v);
    return;
  }
  int i2 = idx - NW;
  if (i2 < 512 * 640) {
    int n = i2 / 640, k2 = i2 - n * 640;
    float v = (k2 < 512) ? Wp[n * 512 + k2] : Wp[n * 512 + k2 - 384];
    Wpx[i2] = f2bf(v);
    return;
  }
  int i3 = i2 - 512 * 640;
  if (i3 < 1792) {
    float v;
    if (i3 < 512)       v = bq[i3];
    else if (i3 < 1024) v = bk[i3 - 512];
    else if (i3 < 1536) v = bv[i3 - 1024];
    else if (i3 < 1664) v = bqml[i3 - 1536];
    else                v = bkml[i3 - 1664];
    bcat[i3] = v;
  }
}

// ---------------- 128x128 QKV projection GEMM, BK=64, swizzled ----------------
__global__ __launch_bounds__(256) void gemm_qkv(
    const u16* __restrict__ A, const u16* __restrict__ Bw,
    const float* __restrict__ bias, u16* __restrict__ Pout, u16* __restrict__ Vtb) {
  __shared__ u16 As[2][8192];
  __shared__ u16 Bs[2][8192];
  const int tid = threadIdx.x;
  const int lane = tid & 63, w = tid >> 6;
  const int g = lane >> 4, c = lane & 15;
  const int n0 = blockIdx.x * 128, m0 = blockIdx.y * 128;
  const int wm = (w >> 1) * 64, wn = (w & 1) * 64;

  f32x4 acc[4][4] = {};
  stage_sw<4>(As[0], A + (size_t)m0 * 512, 512, tid);
  stage_sw<4>(Bs[0], Bw + (size_t)n0 * 512, 512, tid);
  __syncthreads();
  for (int ks = 0; ks < 8; ++ks) {
    int cur = ks & 1;
    if (ks + 1 < 8) {
      stage_sw<4>(As[cur ^ 1], A + (size_t)m0 * 512 + (ks + 1) * 64, 512, tid);
      stage_sw<4>(Bs[cur ^ 1], Bw + (size_t)n0 * 512 + (ks + 1) * 64, 512, tid);
    }
#pragma unroll
    for (int h = 0; h < 2; ++h) {
      bf16x8 av[4], bv[4];
#pragma unroll
      for (int f = 0; f < 4; ++f) {
        av[f] = rd_sw(As[cur], wm + f * 16 + c, h * 64 + g * 16);
        bv[f] = rd_sw(Bs[cur], wn + f * 16 + c, h * 64 + g * 16);
      }
#pragma unroll
      for (int fm = 0; fm < 4; ++fm)
#pragma unroll
        for (int fn = 0; fn < 4; ++fn)
          acc[fm][fn] = __builtin_amdgcn_mfma_f32_16x16x32_bf16(av[fm], bv[fn], acc[fm][fn], 0, 0, 0);
    }
    __syncthreads();
  }

  const bool isV = (n0 >= 1024 && n0 < 1536);
#pragma unroll
  for (int fm = 0; fm < 4; ++fm)
#pragma unroll
    for (int fn = 0; fn < 4; ++fn) {
      int row = m0 + wm + fm * 16 + g * 4;
      int col = n0 + wn + fn * 16 + c;
      float bb = bias[col];
      if (isV) {
        int d = col - 1024;
        int bidx = row >> 10, t = row & 1023;
        us4 pack = { f2bf(acc[fm][fn][0] + bb), f2bf(acc[fm][fn][1] + bb),
                     f2bf(acc[fm][fn][2] + bb), f2bf(acc[fm][fn][3] + bb) };
        *(us4*)&Vtb[((size_t)bidx * 512 + d) * 1024 + t] = pack;
      } else {
        int pcol = (col < 1024) ? col : col - 512;
#pragma unroll
        for (int r = 0; r < 4; ++r)
          Pout[(size_t)(row + r) * PW + pcol] = f2bf(acc[fm][fn][r] + bb);
      }
    }
}

// ---------------- output projection: 128x64 tiles, K=640, swizzled ----------------
__global__ __launch_bounds__(256) void gemm_out(
    const u16* __restrict__ A, const u16* __restrict__ Bw,
    const float* __restrict__ bias, float* __restrict__ Cout) {
  __shared__ u16 As[2][8192];
  __shared__ u16 Bs[2][4096];
  const int tid = threadIdx.x;
  const int lane = tid & 63, w = tid >> 6;
  const int g = lane >> 4, c = lane & 15;
  const int n0 = blockIdx.x * 64, m0 = blockIdx.y * 128;
  const int wm = (w >> 1) * 64, wn = (w & 1) * 32;

  f32x4 acc[4][2] = {};
  stage_sw<4>(As[0], A + (size_t)m0 * 640, 640, tid);
  stage_sw<2>(Bs[0], Bw + (size_t)n0 * 640, 640, tid);
  __syncthreads();
  for (int ks = 0; ks < 10; ++ks) {
    int cur = ks & 1;
    if (ks + 1 < 10) {
      stage_sw<4>(As[cur ^ 1], A + (size_t)m0 * 640 + (ks + 1) * 64, 640, tid);
      stage_sw<2>(Bs[cur ^ 1], Bw + (size_t)n0 * 640 + (ks + 1) * 64, 640, tid);
    }
#pragma unroll
    for (int h = 0; h < 2; ++h) {
      bf16x8 av[4], bv[2];
#pragma unroll
      for (int f = 0; f < 4; ++f)
        av[f] = rd_sw(As[cur], wm + f * 16 + c, h * 64 + g * 16);
#pragma unroll
      for (int f = 0; f < 2; ++f)
        bv[f] = rd_sw(Bs[cur], wn + f * 16 + c, h * 64 + g * 16);
#pragma unroll
      for (int fm = 0; fm < 4; ++fm)
#pragma unroll
        for (int fn = 0; fn < 2; ++fn)
          acc[fm][fn] = __builtin_amdgcn_mfma_f32_16x16x32_bf16(av[fm], bv[fn], acc[fm][fn], 0, 0, 0);
    }
    __syncthreads();
  }
#pragma unroll
  for (int fm = 0; fm < 4; ++fm)
#pragma unroll
    for (int fn = 0; fn < 2; ++fn)
#pragma unroll
      for (int r = 0; r < 4; ++r) {
        int row = m0 + wm + fm * 16 + g * 4 + r;
        int col = n0 + wn + fn * 16 + c;
        Cout[(size_t)row * 512 + col] = acc[fm][fn][r] + bias[col];
      }
}

// ---------------- attention ----------------
// grid (16 qt, 28 units, 4 b):
//  u 0..23 : causal heads 2..7, split 4-way over kv-tiles (kt%4) -> partials
//  u 24,25 : local heads 0,1 (direct)
//  u 26,27 : ml local passes (direct, weighted, Y cols 512..639)
__global__ __launch_bounds__(256) void attn_k(
    const u16* __restrict__ P, const u16* __restrict__ Vtb, u16* __restrict__ Y,
    u16* __restrict__ Part_o, float* __restrict__ Part_ml,
    const float* __restrict__ mix_w, const float* __restrict__ bias_clip,
    const float* __restrict__ bias_clip_ml) {
  __shared__ u16 Ks[2][4096];
  __shared__ u16 Vs[2][4096];
  __shared__ u16 Ps[4][16][72];
  const int tid = threadIdx.x, lane = tid & 63, w = tid >> 6;
  const int g = lane >> 4, c = lane & 15;
  const int qt = blockIdx.x, u = blockIdx.y, b = blockIdx.z;

  int qcol, kcol, vsel, outcol = 0, slot = -1;
  bool localMask = false;
  float kbias, wgt = 1.0f;
  unsigned mask;
  if (u < 24) {
    int h = 2 + (u >> 2), sp = u & 3; slot = u;
    qcol = h * 64; kcol = 512 + h * 64; vsel = h; kbias = bias_clip[h];
    mask = (unsigned)GLOB_M[qt] & (0x1111u << sp);
  } else if (u < 26) {
    int h = u - 24;
    qcol = h * 64; kcol = 512 + h * 64; vsel = h; outcol = h * 64;
    localMask = true; kbias = bias_clip[h];
    mask = LOC_M[qt];
  } else {
    int mh = u - 26;
    qcol = 1024 + mh * 64; kcol = 1152 + mh * 64; vsel = 2 + mh; outcol = 512 + mh * 64;
    localMask = true; kbias = bias_clip_ml[mh]; wgt = mix_w[mh * 2 + 1];
    mask = LOC_M[qt];
  }
  const size_t baseP = (size_t)b * T_SEQ * PW;
  const u16* __restrict__ Kbase = P + baseP + kcol;
  const u16* __restrict__ Vbase = Vtb + ((size_t)b * 512 + vsel * 64) * 1024;
  const int r0 = qt * 64 + w * 16;

  // per-row visibility bounds (verified R3/R4)
  int upmax[4], lomax[4], wminr[4];
#pragma unroll
  for (int r = 0; r < 4; ++r) {
    int row = r0 + g * 4 + r;
    int tqr = (row < 2) ? 0 : ((row < 513) ? 2 * row - 3 : 2 * row - 1024);
    upmax[r] = (tqr - 1) >> 1;
    lomax[r] = (tqr - 2) >> 1;
    wminr[r] = (localMask && row >= 2) ? ((row < 513 ? row - 2 : row - 513) - 3) : -1000000;
  }

  float m[4], l[4];
  f32x4 o[4] = {};
#pragma unroll
  for (int r = 0; r < 4; ++r) { m[r] = -1e8f; l[r] = 0.0f; }

  if (mask) {
    const int qrow = r0 + c;
    bf16x8 aq0 = *(const bf16x8*)&P[baseP + (size_t)qrow * PW + qcol + g * 8];
    bf16x8 aq1 = *(const bf16x8*)&P[baseP + (size_t)qrow * PW + qcol + 32 + g * 8];

    unsigned rem = mask;
    int kt = __ffs(rem) - 1; rem &= rem - 1;
    stage_sw<2>(Ks[0], Kbase + (size_t)(kt * 64) * PW, PW, tid);
    stage_sw<2>(Vs[0], Vbase + kt * 64, 1024, tid);
    __syncthreads();   // implicit vmcnt(0): tile 0 staged
    int cur = 0;

    for (;;) {
      int ktn = -1;
      if (rem) {
        ktn = __ffs(rem) - 1; rem &= rem - 1;
        stage_sw<2>(Ks[cur ^ 1], Kbase + (size_t)(ktn * 64) * PW, PW, tid);
        stage_sw<2>(Vs[cur ^ 1], Vbase + ktn * 64, 1024, tid);
      }

      const int k0 = kt * 64;
      float s[4][4];
#pragma unroll
      for (int cb = 0; cb < 4; ++cb) {
        f32x4 accs = {};
        bf16x8 bk0 = rd_sw(Ks[cur], cb * 16 + c, g * 16);
        bf16x8 bk1 = rd_sw(Ks[cur], cb * 16 + c, 64 + g * 16);
        accs = __builtin_amdgcn_mfma_f32_16x16x32_bf16(aq0, bk0, accs, 0, 0, 0);
        accs = __builtin_amdgcn_mfma_f32_16x16x32_bf16(aq1, bk1, accs, 0, 0, 0);
#pragma unroll
        for (int r = 0; r < 4; ++r) s[cb][r] = accs[r] * 0.125f;
      }
#pragma unroll
      for (int cb = 0; cb < 4; ++cb) {
        int colg = k0 + cb * 16 + c;
        bool tok = colg < 2;
        bool low = colg >= 513;
        int jk = colg - (low ? 513 : 2);
        float addb = (colg == 1) ? kbias : 0.0f;
#pragma unroll
        for (int r = 0; r < 4; ++r) {
          int bnd = low ? lomax[r] : upmax[r];
          bool vis = tok | ((jk <= bnd) & (jk >= wminr[r]));
          s[cb][r] = vis ? (s[cb][r] + addb) : -1e9f;
        }
      }
#pragma unroll
      for (int r = 0; r < 4; ++r) {
        float rmax = fmaxf(fmaxf(s[0][r], s[1][r]), fmaxf(s[2][r], s[3][r]));
        for (int off = 1; off < 16; off <<= 1)
          rmax = fmaxf(rmax, __shfl_xor(rmax, off));
        float mnew = fmaxf(m[r], rmax);
        float fr = __expf(m[r] - mnew);
        float psum = 0.0f;
#pragma unroll
        for (int cb = 0; cb < 4; ++cb) {
          float p = __expf(s[cb][r] - mnew);
          s[cb][r] = p;
          psum += p;
        }
        for (int off = 1; off < 16; off <<= 1)
          psum += __shfl_xor(psum, off);
        l[r] = l[r] * fr + psum;
        m[r] = mnew;
#pragma unroll
        for (int db = 0; db < 4; ++db) o[db][r] *= fr;
      }
#pragma unroll
      for (int cb = 0; cb < 4; ++cb)
#pragma unroll
        for (int r = 0; r < 4; ++r)
          Ps[w][g * 4 + r][cb * 16 + c] = f2bf(s[cb][r]);
      asm volatile("s_waitcnt lgkmcnt(0)" ::: "memory");
      __builtin_amdgcn_sched_barrier(0);
#pragma unroll
      for (int ks2 = 0; ks2 < 2; ++ks2) {
        bf16x8 ap = *(const bf16x8*)&Ps[w][c][ks2 * 32 + g * 8];
#pragma unroll
        for (int db = 0; db < 4; ++db) {
          bf16x8 bv = rd_sw(Vs[cur], db * 16 + c, ks2 * 64 + g * 16);
          o[db] = __builtin_amdgcn_mfma_f32_16x16x32_bf16(ap, bv, o[db], 0, 0, 0);
        }
      }

      if (ktn < 0) break;
      __syncthreads();   // implicit vmcnt(0): next tile staged; buf swap safe
      cur ^= 1; kt = ktn;
    }
  }

  if (slot >= 0) {
    u16* po = Part_o + ((size_t)(slot * 4 + b)) * T_SEQ * 64;
#pragma unroll
    for (int r = 0; r < 4; ++r) {
      int row = r0 + g * 4 + r;
#pragma unroll
      for (int db = 0; db < 4; ++db)
        po[(size_t)row * 64 + db * 16 + c] = f2bf(o[db][r]);
      if (c == 0) {
        size_t mlb = (((size_t)(slot * 4 + b)) * T_SEQ + row) * 2;
        Part_ml[mlb] = m[r];
        Part_ml[mlb + 1] = l[r];
      }
    }
  } else {
    float wl[4];
#pragma unroll
    for (int r = 0; r < 4; ++r) wl[r] = wgt / l[r];
#pragma unroll
    for (int db = 0; db < 4; ++db)
#pragma unroll
      for (int r = 0; r < 4; ++r) {
        int row = r0 + g * 4 + r;
        int col = outcol + db * 16 + c;
        Y[((size_t)b * T_SEQ + row) * 640 + col] = f2bf(o[db][r] * wl[r]);
      }
  }
}

// combine 4-way split partials for heads 2..7 -> Y cols 128..511
__global__ __launch_bounds__(256) void combine_k(
    const u16* __restrict__ Part_o, const float* __restrict__ Part_ml,
    u16* __restrict__ Y, const float* __restrict__ mix_w) {
  int idx = blockIdx.x * 256 + threadIdx.x;  // 6 heads * 4 b * 1024 rows * 16 quads
  int q4 = idx & 15;
  int row = (idx >> 4) & 1023;
  int bb = (idx >> 14) & 3;
  int hp = idx >> 16;
  float mv[4], lv[4];
  float ms = -1e30f;
#pragma unroll
  for (int s = 0; s < 4; ++s) {
    size_t base = (((size_t)(hp * 4 + s) * 4 + bb) * 1024 + row) * 2;
    mv[s] = Part_ml[base];
    lv[s] = Part_ml[base + 1];
    ms = fmaxf(ms, mv[s]);
  }
  float denom = 0.0f, e[4];
#pragma unroll
  for (int s = 0; s < 4; ++s) { e[s] = __expf(mv[s] - ms); denom += lv[s] * e[s]; }
  float wgt = (hp < 2) ? mix_w[hp * 2] : 1.0f;
  float inv = wgt / denom;
  float out[4] = {0.f, 0.f, 0.f, 0.f};
#pragma unroll
  for (int s = 0; s < 4; ++s) {
    us4 ov = *(const us4*)&Part_o[(((size_t)(hp * 4 + s) * 4 + bb) * 1024 + row) * 64 + q4 * 4];
#pragma unroll
    for (int j = 0; j < 4; ++j) out[j] += e[s] * bf2f(ov[j]);
  }
  us4 pk = { f2bf(out[0] * inv), f2bf(out[1] * inv), f2bf(out[2] * inv), f2bf(out[3] * inv) };
  *(us4*)&Y[((size_t)bb * 1024 + row) * 640 + (hp + 2) * 64 + q4 * 4] = pk;
}

extern "C" void kernel_launch(void* const* d_in, const int* in_sizes, int n_in,
                              void* d_out, int out_size, void* d_ws, size_t ws_size,
                              hipStream_t stream) {
  const float* x     = (const float*)d_in[0];
  const float* Wq    = (const float*)d_in[2];
  const float* bq    = (const float*)d_in[3];
  const float* Wk    = (const float*)d_in[4];
  const float* bk    = (const float*)d_in[5];
  const float* Wv    = (const float*)d_in[6];
  const float* bv    = (const float*)d_in[7];
  const float* Wqml  = (const float*)d_in[8];
  const float* bqml  = (const float*)d_in[9];
  const float* Wkml  = (const float*)d_in[10];
  const float* bkml  = (const float*)d_in[11];
  const float* mixw  = (const float*)d_in[12];
  const float* Wp    = (const float*)d_in[13];
  const float* bp    = (const float*)d_in[14];
  const float* bclip = (const float*)d_in[15];
  const float* bclipml = (const float*)d_in[16];

  u16* xb   = (u16*)d_ws;                  // 4096*512
  u16* Wcat = xb + 4096 * 512;             // 1792*512
  u16* Wpx  = Wcat + 1792 * 512;           // 512*640
  u16* Ybuf = Wpx + 512 * 640;             // 4096*640
  u16* Vtb  = Ybuf + 4096 * 640;           // 4*512*1024
  u16* Pbuf = Vtb + 4 * 512 * 1024;        // 4096*1280
  float* bcat = (float*)(Pbuf + 4096 * 1280);  // 2048 f32
  u16* Part_o = (u16*)(bcat + 2048);       // 24*4*1024*64 bf16 = 12.6 MB
  float* Part_ml = (float*)(Part_o + 24 * 4 * 1024 * 64);  // 24*4*1024*2 f32

  prep_all<<<6919, 256, 0, stream>>>((const float4*)x, xb, Wq, Wk, Wv, Wqml, Wkml, Wp,
                                     bq, bk, bv, bqml, bkml, Wcat, Wpx, bcat);
  gemm_qkv<<<dim3(14, 32), 256, 0, stream>>>(xb, Wcat, bcat, Pbuf, Vtb);
  attn_k<<<dim3(16, 28, 4), 256, 0, stream>>>(Pbuf, Vtb, Ybuf, Part_o, Part_ml,
                                              mixw, bclip, bclipml);
  combine_k<<<1536, 256, 0, stream>>>(Part_o, Part_ml, Ybuf, mixw);
  gemm_out<<<dim3(8, 32), 256, 0, stream>>>(Ybuf, Wpx, bp, (float*)d_out);
}